// Round 6
// baseline (181.019 us; speedup 1.0000x reference)
//
#include <hip/hip_runtime.h>
#include <hip/hip_bf16.h>

#define BB 4
#define SS 32
#define HH 8
#define LL 128
#define DD 512
#define DI 2048
#define EPSN 1e-6f
#define INV_TEMP 0.04419417382415922f   // 1/sqrt(512)

#define NLOGIT_BLK 4096                  // B*S*L / 4 waves
#define NCAST_GRAN ((DI*DD/4)*2 + (DD*DD/4))   // 589824 float4 granules
#define NCAST_BLK (NCAST_GRAN / 256)     // 2304

#define NROW (BB*SS*HH)                  // 1024 rows
#define SLICE ((size_t)NROW * DD)        // 524288 floats per K-split partial
#define SXAP (DD + 8)                    // padded sxa row (bank-conflict fix)

typedef __attribute__((ext_vector_type(8))) short short8;
typedef __attribute__((ext_vector_type(4))) float float4v;

static __device__ __forceinline__ unsigned short f2b(float f) {
  __hip_bfloat16 h = __float2bfloat16(f);
  return *(unsigned short*)&h;
}

// ---------------------------------------------------------------------------
// K1: fused [logits] + [weight cast].
//   blocks [0,4096): one wave per (bs,l); 8 head-dots, shuffle reduce.
//   blocks [4096,6400): fp32->bf16 cast of w1,w2,v_w.
// ---------------------------------------------------------------------------
__global__ __launch_bounds__(256) void pre_kernel(
    const float* __restrict__ x, const int* __restrict__ mask,
    const float* __restrict__ w, const float* __restrict__ w1,
    const float* __restrict__ w2, const float* __restrict__ v_w,
    unsigned short* __restrict__ w1b, unsigned short* __restrict__ w2b,
    unsigned short* __restrict__ v_wb, float* __restrict__ logits) {
  int blk = blockIdx.x;
  if (blk < NLOGIT_BLK) {
    int wv = threadIdx.x >> 6, lane = threadIdx.x & 63;
    int p  = blk * 4 + wv;           // (bs,l) pair index
    int bs = p >> 7, l = p & (LL - 1);

    const float4* xr = (const float4*)(x + ((size_t)bs * LL + l) * DD) + lane * 2;
    float4 x0 = xr[0], x1 = xr[1];

    float acc[HH];
#pragma unroll
    for (int h = 0; h < HH; ++h) {
      const float4* wr = (const float4*)(w + ((size_t)h * LL + l) * DD) + lane * 2;
      float4 w0 = wr[0], w1v = wr[1];
      acc[h] = x0.x * w0.x + x0.y * w0.y + x0.z * w0.z + x0.w * w0.w +
               x1.x * w1v.x + x1.y * w1v.y + x1.z * w1v.z + x1.w * w1v.w;
    }
#pragma unroll
    for (int off = 32; off > 0; off >>= 1) {
#pragma unroll
      for (int h = 0; h < HH; ++h) acc[h] += __shfl_xor(acc[h], off);
    }
    if (lane == 0) {
      int msk = mask[bs * LL + l];
#pragma unroll
      for (int h = 0; h < HH; ++h) {
        float lg = msk ? acc[h] * INV_TEMP : -1e9f;
        logits[((size_t)bs * HH + h) * LL + l] = lg;
      }
    }
  } else {
    const int n1 = (DI * DD) / 4;    // w1 granules
    const int n2 = n1;               // w2
    int i = (blk - NLOGIT_BLK) * 256 + threadIdx.x;
    const float4* src;
    unsigned short* dst;
    int j = i;
    if (i < n1)           { src = (const float4*)w1;  dst = w1b; }
    else if (i < n1 + n2) { src = (const float4*)w2;  dst = w2b;  j = i - n1; }
    else                  { src = (const float4*)v_w; dst = v_wb; j = i - n1 - n2; }
    float4 v = src[j];
    dst[j * 4 + 0] = f2b(v.x);
    dst[j * 4 + 1] = f2b(v.y);
    dst[j * 4 + 2] = f2b(v.z);
    dst[j * 4 + 3] = f2b(v.w);
  }
}

// ---------------------------------------------------------------------------
// K2: fused softmax + xa + (xa @ v_w^T via MFMA) + mid LayerNorm.
// One block per (b,s): grid 128, 512 threads (8 waves).
//   P1: softmax on logits (waves 0-3), write attn output.
//   P2: xa[h][e] = sum_l attn*x, thread-per-column, bf16 into LDS.
//   P3: MFMA 16x16x32: A=sxa (rows 0-7 valid), B=v_w rows streamed from L2;
//       wave wv owns output cols [wv*64, wv*64+64).
//   P4: LN per row (wave r = row r), write o_ln fp32 + o_lnb bf16.
// ---------------------------------------------------------------------------
__global__ __launch_bounds__(512) void xa_v_ln_kernel(
    const float* __restrict__ x, const float* __restrict__ logits,
    const unsigned short* __restrict__ v_wb, const float* __restrict__ ln_g,
    const float* __restrict__ ln_b, float* __restrict__ attn_out,
    float* __restrict__ o_ln, unsigned short* __restrict__ o_lnb) {
  int bs = blockIdx.x;
  int t = threadIdx.x, wv = t >> 6, lane = t & 63;

  __shared__ float sattn_t[LL][HH];            // 4 KB
  __shared__ unsigned short sxa[16][SXAP];     // 16.25 KB (padded, bf16)
  __shared__ float sout[HH][DD];               // 16 KB

  // P1: softmax; wave wv (0-3) handles heads wv and wv+4
  if (wv < 4) {
    for (int h = wv; h < HH; h += 4) {
      const float* lg = logits + ((size_t)bs * HH + h) * LL;
      float v0 = lg[lane], v1 = lg[lane + 64];
      float m = fmaxf(v0, v1);
#pragma unroll
      for (int off = 32; off > 0; off >>= 1) m = fmaxf(m, __shfl_xor(m, off));
      float e0 = __expf(v0 - m), e1 = __expf(v1 - m);
      float s = e0 + e1;
#pragma unroll
      for (int off = 32; off > 0; off >>= 1) s += __shfl_xor(s, off);
      float inv = 1.f / s;
      e0 *= inv; e1 *= inv;
      sattn_t[lane][h]      = e0;
      sattn_t[lane + 64][h] = e1;
      float* ao = attn_out + ((size_t)bs * HH + h) * LL;
      ao[lane]      = e0;
      ao[lane + 64] = e1;
    }
  }
  __syncthreads();

  // P2: xa; thread owns column e = t (sattn reads broadcast, x coalesced)
  {
    int e = t;
    const float* xb = x + (size_t)bs * LL * DD;
    float acc[HH];
#pragma unroll
    for (int h = 0; h < HH; ++h) acc[h] = 0.f;
    for (int l = 0; l < LL; ++l) {
      float xv = xb[(size_t)l * DD + e];
      float4 a0 = *(const float4*)&sattn_t[l][0];
      float4 a1 = *(const float4*)&sattn_t[l][4];
      acc[0] += a0.x * xv; acc[1] += a0.y * xv;
      acc[2] += a0.z * xv; acc[3] += a0.w * xv;
      acc[4] += a1.x * xv; acc[5] += a1.y * xv;
      acc[6] += a1.z * xv; acc[7] += a1.w * xv;
    }
#pragma unroll
    for (int h = 0; h < HH; ++h) sxa[h][e] = f2b(acc[h]);
  }
  __syncthreads();

  // P3: out[0:8][n] = sxa(0:8 valid) @ v_w^T; wave wv owns cols wv*64..+63.
  // Rows 8-15 of A are garbage but only pollute D rows 8-15 (discarded).
  {
    int lm = lane & 15, lq = lane >> 4;
    int n0 = wv * 64;
    const short8* Bp[4];
#pragma unroll
    for (int nf = 0; nf < 4; ++nf)
      Bp[nf] = (const short8*)(v_wb + (size_t)(n0 + nf * 16 + lm) * DD);

    float4v acc[4];
#pragma unroll
    for (int nf = 0; nf < 4; ++nf) acc[nf] = (float4v){0.f, 0.f, 0.f, 0.f};

#pragma unroll 4
    for (int ks = 0; ks < DD / 32; ++ks) {
      short8 a0 = *(const short8*)&sxa[lm][ks * 32 + lq * 8];
      short8 b[4];
#pragma unroll
      for (int nf = 0; nf < 4; ++nf) b[nf] = Bp[nf][ks * 4 + lq];
#pragma unroll
      for (int nf = 0; nf < 4; ++nf)
        acc[nf] = __builtin_amdgcn_mfma_f32_16x16x32_bf16(a0, b[nf], acc[nf], 0, 0, 0);
    }

#pragma unroll
    for (int nf = 0; nf < 4; ++nf) {
      int col = n0 + nf * 16 + lm;
#pragma unroll
      for (int r = 0; r < 4; ++r) {
        int row = lq * 4 + r;
        if (row < HH) sout[row][col] = acc[nf][r];
      }
    }
  }
  __syncthreads();

  // P4: LayerNorm, wave r = row r (8 waves, 8 rows)
  {
    int r = wv;
    float vals[8];
    float sum = 0.f, sq = 0.f;
#pragma unroll
    for (int k = 0; k < 8; ++k) {
      float v = sout[r][lane + 64 * k];
      vals[k] = v;
      sum += v;
      sq += v * v;
    }
#pragma unroll
    for (int off = 32; off > 0; off >>= 1) {
      sum += __shfl_xor(sum, off);
      sq  += __shfl_xor(sq, off);
    }
    float mu  = sum * (1.f / DD);
    float var = sq * (1.f / DD) - mu * mu;
    float rs  = rsqrtf(var + EPSN);
    float* op = o_ln + ((size_t)bs * HH + r) * DD;
    unsigned short* opb = o_lnb + ((size_t)bs * HH + r) * DD;
#pragma unroll
    for (int k = 0; k < 8; ++k) {
      int d = lane + 64 * k;
      float v = (vals[k] - mu) * rs * ln_g[d] + ln_b[d];
      op[d]  = v;
      opb[d] = f2b(v);
    }
  }
}

// ---------------------------------------------------------------------------
// K3: GEMM1  h1 = relu(xln @ w1^T + b1).  M=1024 N=2048 K=512.
// Block 64x64, 4 waves (16Mx64N).  grid = 16*32 = 512.
// ---------------------------------------------------------------------------
__global__ __launch_bounds__(256) void gemm1_kernel(
    const unsigned short* __restrict__ xb, const unsigned short* __restrict__ w1b,
    const float* __restrict__ b1, unsigned short* __restrict__ h1b) {
  int blk = blockIdx.x;
  int nt = blk & 31, mt = blk >> 5;
  int wv = threadIdx.x >> 6, lane = threadIdx.x & 63;
  int lm = lane & 15, lq = lane >> 4;

  int m0 = mt * 64 + wv * 16;
  int n0 = nt * 64;

  const short8* A0 = (const short8*)(xb + (size_t)(m0 + lm) * DD);
  const short8* Bp[4];
#pragma unroll
  for (int nf = 0; nf < 4; ++nf)
    Bp[nf] = (const short8*)(w1b + (size_t)(n0 + nf * 16 + lm) * DD);

  float4v acc[4];
#pragma unroll
  for (int nf = 0; nf < 4; ++nf) acc[nf] = (float4v){0.f, 0.f, 0.f, 0.f};

#pragma unroll 4
  for (int ks = 0; ks < DD / 32; ++ks) {
    short8 a0 = A0[ks * 4 + lq];
    short8 b[4];
#pragma unroll
    for (int nf = 0; nf < 4; ++nf) b[nf] = Bp[nf][ks * 4 + lq];
#pragma unroll
    for (int nf = 0; nf < 4; ++nf)
      acc[nf] = __builtin_amdgcn_mfma_f32_16x16x32_bf16(a0, b[nf], acc[nf], 0, 0, 0);
  }

#pragma unroll
  for (int nf = 0; nf < 4; ++nf) {
    int col = n0 + nf * 16 + lm;
    float bb = b1[col];
#pragma unroll
    for (int r = 0; r < 4; ++r) {
      int row = m0 + lq * 4 + r;
      float v = acc[nf][r] + bb;
      h1b[(size_t)row * DI + col] = f2b(fmaxf(v, 0.f));
    }
  }
}

// ---------------------------------------------------------------------------
// K4: GEMM2  ypart[ks] = h1 @ w2^T (K-chunk ks).  M=1024 N=512 K=2048.
// Block 64x64, 4 waves, K-split x4 (chunk=512).  grid=512.
// ---------------------------------------------------------------------------
__global__ __launch_bounds__(256) void gemm2_kernel(
    const unsigned short* __restrict__ h1b, const unsigned short* __restrict__ w2b,
    float* __restrict__ ypart) {
  int blk = blockIdx.x;
  int nt = blk & 7, mt = (blk >> 3) & 15, kslice = blk >> 7;
  int wv = threadIdx.x >> 6, lane = threadIdx.x & 63;
  int lm = lane & 15, lq = lane >> 4;

  int m0 = mt * 64 + wv * 16;
  int n0 = nt * 64;
  int g0 = kslice * 64;   // short8 granule offset (512 elems)

  const short8* A0 = (const short8*)(h1b + (size_t)(m0 + lm) * DI) + g0;
  const short8* Bp[4];
#pragma unroll
  for (int nf = 0; nf < 4; ++nf)
    Bp[nf] = (const short8*)(w2b + (size_t)(n0 + nf * 16 + lm) * DI) + g0;

  float4v acc[4];
#pragma unroll
  for (int nf = 0; nf < 4; ++nf) acc[nf] = (float4v){0.f, 0.f, 0.f, 0.f};

#pragma unroll 4
  for (int ks = 0; ks < 16; ++ks) {
    short8 a0 = A0[ks * 4 + lq];
    short8 b[4];
#pragma unroll
    for (int nf = 0; nf < 4; ++nf) b[nf] = Bp[nf][ks * 4 + lq];
#pragma unroll
    for (int nf = 0; nf < 4; ++nf)
      acc[nf] = __builtin_amdgcn_mfma_f32_16x16x32_bf16(a0, b[nf], acc[nf], 0, 0, 0);
  }

  float* outp = ypart + (size_t)kslice * SLICE;
#pragma unroll
  for (int nf = 0; nf < 4; ++nf) {
    int col = n0 + nf * 16 + lm;
#pragma unroll
    for (int r = 0; r < 4; ++r) {
      int row = m0 + lq * 4 + r;
      outp[(size_t)row * DD + col] = acc[nf][r];
    }
  }
}

// ---------------------------------------------------------------------------
// K5: final LN:  y = LN(sum ypart + b2 + o_ln)*g + b.
// ---------------------------------------------------------------------------
__global__ __launch_bounds__(256) void ln_final_kernel(
    const float* __restrict__ ypart, const float* __restrict__ o_ln,
    const float* __restrict__ b2, const float* __restrict__ fln_g,
    const float* __restrict__ fln_b, float* __restrict__ y_out) {
  int wv = threadIdx.x >> 6, lane = threadIdx.x & 63;
  int row = blockIdx.x * 4 + wv;

  const float* p0 = ypart + (size_t)row * DD;
  const float* ol = o_ln + (size_t)row * DD;
  float vals[8];
  float sum = 0.f, sq = 0.f;
#pragma unroll
  for (int k = 0; k < 8; ++k) {
    int d = lane + 64 * k;
    float v = p0[d] + p0[SLICE + d] + p0[2 * SLICE + d] + p0[3 * SLICE + d] +
              b2[d] + ol[d];
    vals[k] = v;
    sum += v;
    sq += v * v;
  }
#pragma unroll
  for (int off = 32; off > 0; off >>= 1) {
    sum += __shfl_xor(sum, off);
    sq  += __shfl_xor(sq, off);
  }
  float mu  = sum * (1.f / DD);
  float var = sq * (1.f / DD) - mu * mu;
  float rs  = rsqrtf(var + EPSN);
  float* yo = y_out + (size_t)row * DD;
#pragma unroll
  for (int k = 0; k < 8; ++k) {
    int d = lane + 64 * k;
    yo[d] = (vals[k] - mu) * rs * fln_g[d] + fln_b[d];
  }
}

extern "C" void kernel_launch(void* const* d_in, const int* in_sizes, int n_in,
                              void* d_out, int out_size, void* d_ws, size_t ws_size,
                              hipStream_t stream) {
  const float* x     = (const float*)d_in[0];
  const int*   mask  = (const int*)d_in[1];
  const float* w     = (const float*)d_in[2];
  const float* v_w   = (const float*)d_in[3];
  const float* ln_g  = (const float*)d_in[4];
  const float* ln_b  = (const float*)d_in[5];
  const float* w1    = (const float*)d_in[6];
  const float* b1    = (const float*)d_in[7];
  const float* w2    = (const float*)d_in[8];
  const float* b2    = (const float*)d_in[9];
  const float* fln_g = (const float*)d_in[10];
  const float* fln_b = (const float*)d_in[11];

  float* y    = (float*)d_out;
  float* attn = y + (size_t)BB * SS * HH * DD;

  // workspace layout (bytes)
  char* ws = (char*)d_ws;
  float*          o_ln    = (float*)(ws);                       // 2 MB
  unsigned short* o_lnb   = (unsigned short*)(ws + 2097152);    // 1 MB
  unsigned short* w1b     = (unsigned short*)(ws + 3145728);    // 2 MB
  unsigned short* w2b     = (unsigned short*)(ws + 5242880);    // 2 MB
  unsigned short* h1b     = (unsigned short*)(ws + 7340032);    // 4 MB
  float*          ypart   = (float*)(ws + 11534336);            // 8 MB (4 slices)
  unsigned short* v_wb    = (unsigned short*)(ws + 19922944);   // 512 KB
  float*          logits  = (float*)(ws + 20447232);            // 512 KB

  pre_kernel<<<NLOGIT_BLK + NCAST_BLK, 256, 0, stream>>>(
      x, mask, w, w1, w2, v_w, w1b, w2b, v_wb, logits);
  xa_v_ln_kernel<<<BB * SS, 512, 0, stream>>>(
      x, logits, v_wb, ln_g, ln_b, attn, o_ln, o_lnb);
  gemm1_kernel<<<512, 256, 0, stream>>>(o_lnb, w1b, b1, h1b);
  gemm2_kernel<<<512, 256, 0, stream>>>(h1b, w2b, ypart);
  ln_final_kernel<<<256, 256, 0, stream>>>(ypart, o_ln, b2, fln_g, fln_b, y);
}